// Round 8
// baseline (553.685 us; speedup 1.0000x reference)
//
#include <hip/hip_runtime.h>

typedef __bf16 bf16x8 __attribute__((ext_vector_type(8)));
typedef float  f32x4  __attribute__((ext_vector_type(4)));
typedef float  f32x2  __attribute__((ext_vector_type(2)));
typedef unsigned int u32x4 __attribute__((ext_vector_type(4)));
typedef unsigned short u16;

#define NPTS 8192
#define NB   4
#define KNN  16
#define ROW  136        // u16 per row; 272 B = 17 x 16B
#define CF   131
#define JBLK 136
#define NSTEP 34        // K = 1088 = 34*32
#define AGG_STRIDE 1096 // u16 (2192 B per point)
#define HALF_U16 8704   // 64 rows * 136 u16 per ping-pong half
#define WOFF  17408     // u16 idx: w bf16 [16p][16k][8j]
#define RBOFF 19456     // u16 idx: rb table (u16[256])
#define SMEM_U16 19712  // 39424 B total
// phase-C tail aliases (all inside dead rowbuf/agg region)
#define F2T   0         // u16[16][128]
#define H1OFF 2304      // u16, stride 136
#define FFOFF 4608      // u16 idx -> float* (byte 9216), stride 68 floats
#define NEG 0.1f
#define NBLK 512        // grid: 2 blocks/CU guaranteed co-resident (LDS cap 4/CU)

#define WAITVM(n) __builtin_amdgcn_s_waitcnt(0x0F70 | (n))
#define SB() __builtin_amdgcn_sched_barrier(0)

__device__ __forceinline__ float b2f(u16 h) {
    return __uint_as_float(((unsigned int)h) << 16);
}
// round-half-up: 2 insts; <=1 ulp bf16
__device__ __forceinline__ u16 f2bf(float f) {
    unsigned int u = __float_as_uint(f);
    return (u16)((u + 0x8000u) >> 16);
}
__device__ __forceinline__ void dma16(const u16* g, u16* l) {
    __builtin_amdgcn_global_load_lds(
        (const __attribute__((address_space(1))) void*)g,
        (__attribute__((address_space(3))) void*)l, 16, 0, 0);
}
__device__ __forceinline__ float lrelu(float v) {
    return (v < 0.0f) ? NEG * v : v;
}

// ---------------------------------------------------------------------------
// Device-scope generation barrier. Module-load zero-init; generation counter
// only ever increments, so repeated graph replays of the same launch are safe
// (no re-init needed). Release/acquire + __threadfence give cross-XCD
// visibility (G16): releaser's fence writes back L2, waiters' fence
// invalidates before any phase-N+1 read.
__device__ unsigned g_cnt = 0;
__device__ unsigned g_gen = 0;

__device__ __forceinline__ void global_barrier() {
    __syncthreads();
    __threadfence();   // all waves: flush prior global writes device-scope
    if (threadIdx.x == 0) {
        unsigned g = __hip_atomic_load(&g_gen, __ATOMIC_RELAXED,
                                       __HIP_MEMORY_SCOPE_AGENT);
        unsigned a = __hip_atomic_fetch_add(&g_cnt, 1u, __ATOMIC_ACQ_REL,
                                            __HIP_MEMORY_SCOPE_AGENT);
        if (a == (unsigned)(NBLK - 1)) {
            __hip_atomic_store(&g_cnt, 0u, __ATOMIC_RELAXED,
                               __HIP_MEMORY_SCOPE_AGENT);
            __hip_atomic_store(&g_gen, g + 1u, __ATOMIC_RELEASE,
                               __HIP_MEMORY_SCOPE_AGENT);
        } else {
            while (__hip_atomic_load(&g_gen, __ATOMIC_ACQUIRE,
                                     __HIP_MEMORY_SCOPE_AGENT) == g) {
                __builtin_amdgcn_s_sleep(8);
            }
        }
        __threadfence();   // acquire side: invalidate CU caches
    }
    __syncthreads();
}

// ---------------------------------------------------------------------------
// Core: gather (pipelined DMA) + weight-net + einsum + MFMA GEMM vs lwP.
// (Exact round-0 structure: 2 barriers, WAITVM depth 5.)
__device__ __forceinline__ void pc_core(
    u16* __restrict__ smem,
    const u16* __restrict__ fcT, const float* __restrict__ xyzF,
    const int* __restrict__ knn, const float* __restrict__ wn_w,
    const float* __restrict__ wn_b, const u16* __restrict__ lwP,
    int pt0, int b, int n0, f32x4& acc1o, f32x4& acc2o)
{
    int t = threadIdx.x;
    int wv = t >> 6, lane = t & 63;
    int p = t >> 4, cl = t & 15;
    u16* rb16 = smem + RBOFF;

    // ---- P0 (wave-local): indices, rel coords, weight-net -> bf16 LDS ----
    {
        size_t rowC = (size_t)b * NPTS + n0 + p;
        int idxv = knn[rowC * KNN + cl];
        int rb = b * NPTS + idxv;
        rb16[p * 16 + cl] = (u16)rb;
        f32x4 cx = *(const f32x4*)(xyzF + rowC * 4);
        f32x4 nx = *(const f32x4*)(xyzF + (size_t)rb * 4);
        float rx = nx[0] - cx[0], ry = nx[1] - cx[1], rz = nx[2] - cx[2];
        unsigned int wp[4];
        #pragma unroll
        for (int jj = 0; jj < 4; jj++) {
            float a0 = lrelu(wn_w[(2 * jj) * 3 + 0] * rx + wn_w[(2 * jj) * 3 + 1] * ry +
                             wn_w[(2 * jj) * 3 + 2] * rz + wn_b[2 * jj]);
            float a1 = lrelu(wn_w[(2 * jj + 1) * 3 + 0] * rx + wn_w[(2 * jj + 1) * 3 + 1] * ry +
                             wn_w[(2 * jj + 1) * 3 + 2] * rz + wn_b[2 * jj + 1]);
            wp[jj] = (unsigned)f2bf(a0) | ((unsigned)f2bf(a1) << 16);
        }
        *(u32x4*)(smem + WOFF + (p * 16 + cl) * 8) = (u32x4){wp[0], wp[1], wp[2], wp[3]};
    }

    f32x2 acc[4][8];
    float acct[8];
    #pragma unroll
    for (int i = 0; i < 4; i++)
        #pragma unroll
        for (int j = 0; j < 8; j++) acc[i][j] = (f32x2){0.f, 0.f};
    #pragma unroll
    for (int j = 0; j < 8; j++) acct[j] = 0.f;

    // ---- hoisted DMA slot decomposition (chunk-invariant) ----
    int rbidx[5], remu[5], ldso[5];
    #pragma unroll
    for (int i = 0; i < 5; i++) {
        int slot = i * 64 + lane;
        int rl = slot / 17;              // 0..15 (row within wave's chunk)
        int rem = slot - rl * 17;        // 0..16 (16B unit within row)
        int pp = wv * 4 + (rl >> 2);
        int kk = rl & 3;
        rbidx[i] = pp * 16 + kk;         // + c*4 per chunk
        remu[i] = rem * 8;               // u16 offset in row
        ldso[i] = (pp * 4 + kk) * 136 + rem * 8;
    }

    auto issue = [&](int c) {
        int h = c & 1;
        #pragma unroll
        for (int i = 0; i < 5; i++) {
            if (i < 4 || lane < 16) {
                int rb = (int)rb16[rbidx[i] + c * 4];
                dma16(fcT + (size_t)rb * ROW + remu[i],
                      smem + h * HALF_U16 + ldso[i]);
            }
        }
    };
    // consume chunk c: einsum over its 4 k's (LDS only)
    auto consume = [&](int c) {
        int h = c & 1;
        const u16* rpb = smem + h * HALF_U16 + p * (4 * 136);
        const u16* wpb = smem + WOFF + (p * 16 + c * 4) * 8;
        #pragma unroll 2
        for (int kk = 0; kk < 4; kk++) {
            u32x4 rv = *(const u32x4*)(rpb + kk * 136 + cl * 8);
            float tl = (cl < 3) ? b2f(rpb[kk * 136 + 128 + cl]) : 0.0f;
            u32x4 wv4 = *(const u32x4*)(wpb + kk * 8);
            f32x2 v[4];
            float wr[8];
            #pragma unroll
            for (int i = 0; i < 4; i++) {
                unsigned int u = rv[i];
                v[i] = (f32x2){__uint_as_float(u << 16),
                               __uint_as_float(u & 0xFFFF0000u)};
                unsigned int uw = wv4[i];
                wr[2 * i]     = __uint_as_float(uw << 16);
                wr[2 * i + 1] = __uint_as_float(uw & 0xFFFF0000u);
            }
            #pragma unroll
            for (int j = 0; j < 8; j++) {
                f32x2 w2 = (f32x2){wr[j], wr[j]};
                #pragma unroll
                for (int i = 0; i < 4; i++) acc[i][j] += v[i] * w2;
                acct[j] += tl * wr[j];
            }
        }
    };

    issue(0); issue(1);
    #pragma unroll 1
    for (int c = 0; c < 2; c++) {
        WAITVM(5); SB(); consume(c); SB(); issue(c + 2); SB();
    }
    WAITVM(5); SB(); consume(2); SB();
    WAITVM(0); SB(); consume(3);
    __syncthreads();   // all einsum reads done before agg overwrites rowbuf

    // ---- agg write (bf16, k-hat layout) ----
    {
        #pragma unroll
        for (int j = 0; j < 8; j++) {
            unsigned int o[4];
            #pragma unroll
            for (int i = 0; i < 4; i++) {
                unsigned int lo = f2bf(acc[i][j].x);
                unsigned int hi = f2bf(acc[i][j].y);
                o[i] = lo | (hi << 16);
            }
            *(u32x4*)(smem + p * AGG_STRIDE + j * JBLK + cl * 8) =
                (u32x4){o[0], o[1], o[2], o[3]};
        }
        if (cl < 3) {
            #pragma unroll
            for (int j = 0; j < 8; j++)
                smem[p * AGG_STRIDE + j * JBLK + 128 + cl] = f2bf(acct[j]);
        }
        if (cl < 5) {
            #pragma unroll
            for (int j = 0; j < 8; j++)
                smem[p * AGG_STRIDE + j * JBLK + CF + cl] = 0;
        }
    }
    __syncthreads();

    // ---- MFMA: out[16][128] = agg @ lin_w^T. Rolled, unroll-4 ----
    {
        int m = lane & 15, quad = lane >> 4;
        f32x4 a1 = {0.f, 0.f, 0.f, 0.f};
        f32x4 a2 = {0.f, 0.f, 0.f, 0.f};
        #pragma unroll 4
        for (int s = 0; s < NSTEP; s++) {
            u32x4 av = *(const u32x4*)(smem + m * AGG_STRIDE + s * 32 + quad * 8);
            u32x4 bv1 = *(const u32x4*)(lwP + (((size_t)(s * 8 + wv) * 64 + lane) << 3));
            u32x4 bv2 = *(const u32x4*)(lwP + (((size_t)(s * 8 + wv + 4) * 64 + lane) << 3));
            a1 = __builtin_amdgcn_mfma_f32_16x16x32_bf16(
                __builtin_bit_cast(bf16x8, av), __builtin_bit_cast(bf16x8, bv1), a1, 0, 0, 0);
            a2 = __builtin_amdgcn_mfma_f32_16x16x32_bf16(
                __builtin_bit_cast(bf16x8, av), __builtin_bit_cast(bf16x8, bv2), a2, 0, 0, 0);
        }
        acc1o = a1; acc2o = a2;
    }
}

// ---------------------------------------------------------------------------
// Fused kernel, plain launch: phase A (pack) -> global_barrier -> phase B
// (pc0 x4 tiles) -> global_barrier -> phase C (pc1+MLP x4 tiles).
// Grid = 512 blocks = 2/CU (the residency rocprof shows in every passing
// round; LDS capacity is 4/CU, so co-residency has 2x margin).
__global__ __launch_bounds__(256, 2) void fused_all(
    const float* __restrict__ xyz, const float* __restrict__ feat,
    const int* __restrict__ knn,
    const float* __restrict__ wn1_w, const float* __restrict__ wn1_b,
    const float* __restrict__ lin1w, const float* __restrict__ lin1b,
    const float* __restrict__ wn2_w, const float* __restrict__ wn2_b,
    const float* __restrict__ lin2w, const float* __restrict__ lin2b,
    const float* __restrict__ m1_w, const float* __restrict__ m1_b,
    const float* __restrict__ m2_w, const float* __restrict__ m2_b,
    const float* __restrict__ cl_w, const float* __restrict__ cl_b,
    float* __restrict__ dout,
    u16* __restrict__ fcT1, u16* __restrict__ fcT2, float* __restrict__ xyzF,
    u16* __restrict__ lw1P, u16* __restrict__ lw2P,
    u16* __restrict__ m1P, u16* __restrict__ m2P)
{
    __shared__ __align__(16) u16 smem[SMEM_U16];
    int t = threadIdx.x;
    int blk = blockIdx.x;

    // ================= Phase A: pack (verbatim r6 bodies) =================
    {
        u16* tile = smem;                 // CF*65 = 8515 u16, aliases rowbuf
        int b = blk >> 7;
        int n0 = (blk & 127) << 6;
        int nn = t & 63;
        #pragma unroll 1
        for (int c = (t >> 6); c < CF; c += 4) {
            float v;
            if (c < 3) v = xyz[(size_t)b * 3 * NPTS + (size_t)c * NPTS + n0 + nn];
            else       v = feat[(size_t)b * 128 * NPTS + (size_t)(c - 3) * NPTS + n0 + nn];
            tile[c * 65 + nn] = f2bf(v);
            if (c < 3) xyzF[((size_t)b * NPTS + n0 + nn) * 4 + c] = v;
        }
        __syncthreads();
        // 64 rows x 17 ushort8 units; fcT2 needs only units 0 and 16.
        #pragma unroll 1
        for (int e = t; e < 64 * 17; e += 256) {
            int r = e / 17;
            int u = e - r * 17;
            int c0 = u * 8;
            unsigned int w[4];
            #pragma unroll
            for (int i = 0; i < 4; i++) {
                int ca = c0 + 2 * i, cb = ca + 1;
                unsigned lo = (ca < CF) ? (unsigned)tile[ca * 65 + r] : 0u;
                unsigned hi = (cb < CF) ? (unsigned)tile[cb * 65 + r] : 0u;
                w[i] = lo | (hi << 16);
            }
            size_t row = (size_t)b * NPTS + n0 + r;
            *(u32x4*)(fcT1 + row * ROW + c0) = (u32x4){w[0], w[1], w[2], w[3]};
            if (u == 0 || u == 16)
                *(u32x4*)(fcT2 + row * ROW + c0) = (u32x4){w[0], w[1], w[2], w[3]};
        }
        // weight packs on blocks 0..147 (no LDS use)
        if (blk < 148) {
            const float* w; u16* out; int O, Cin, remap, b0;
            if (blk < 68)       { w = lin1w; out = lw1P; O = 128; Cin = 1048; remap = 1; b0 = 0; }
            else if (blk < 136) { w = lin2w; out = lw2P; O = 128; Cin = 1048; remap = 1; b0 = 68; }
            else if (blk < 144) { w = m1_w;  out = m1P;  O = 128; Cin = 128;  remap = 0; b0 = 136; }
            else                { w = m2_w;  out = m2P;  O = 64;  Cin = 128;  remap = 0; b0 = 144; }
            int T = O >> 4;
            int tid = (blk - b0) * 256 + t;
            int l = tid & 63;
            int st = tid >> 6;
            int tt = st % T;
            int s = st / T;
            int o = tt * 16 + (l & 15);
            int kb = s * 32 + ((l >> 4) * 8);
            #pragma unroll 1
            for (int j = 0; j < 8; j++) {
                int kh = kb + j;
                u16 v = 0;
                if (remap) {
                    int jj = kh / JBLK, cc = kh - jj * JBLK;
                    if (cc < CF) v = f2bf(w[(size_t)o * Cin + jj * CF + cc]);
                } else {
                    if (kh < Cin) v = f2bf(w[(size_t)o * Cin + kh]);
                }
                out[(size_t)tid * 8 + j] = v;
            }
        }
    }
    global_barrier();

    // ================= Phase B: pc0, 4 tiles per block ====================
    {
        int wv = t >> 6, lane = t & 63;
        int col = lane & 15, quad = lane >> 4;
        #pragma unroll 1
        for (int tl = blk; tl < (NB * NPTS / 16); tl += NBLK) {
            int pt0 = tl * 16;
            int b = pt0 >> 13;
            int n0 = pt0 & (NPTS - 1);
            f32x4 a1, a2;
            pc_core(smem, fcT1, xyzF, knn, wn1_w, wn1_b, lw1P, pt0, b, n0, a1, a2);
            int o1 = wv * 16 + col, o2 = (wv + 4) * 16 + col;
            float bb1 = lin1b[o1], bb2 = lin1b[o2];
            #pragma unroll
            for (int r = 0; r < 4; r++) {
                int prow = pt0 + quad * 4 + r;
                fcT2[(size_t)prow * ROW + 3 + o1] = f2bf(lrelu(a1[r] + bb1));
                fcT2[(size_t)prow * ROW + 3 + o2] = f2bf(lrelu(a2[r] + bb2));
            }
            __syncthreads();   // agg region dead before next tile's DMA/P0
        }
    }
    global_barrier();

    // ================= Phase C: pc1 + MLP head, 4 tiles per block =========
    {
        int wv = t >> 6, lane = t & 63;
        int col = lane & 15, quad = lane >> 4;
        int m = lane & 15;
        #pragma unroll 1
        for (int tl = blk; tl < (NB * NPTS / 16); tl += NBLK) {
            int pt0 = tl * 16;
            int b = pt0 >> 13;
            int n0 = pt0 & (NPTS - 1);
            f32x4 a1, a2;
            pc_core(smem, fcT2, xyzF, knn, wn2_w, wn2_b, lw2P, pt0, b, n0, a1, a2);

            // f2 tile -> LDS (agg region done being read after this barrier)
            {
                int o1 = wv * 16 + col, o2 = (wv + 4) * 16 + col;
                float bb1 = lin2b[o1], bb2 = lin2b[o2];
                __syncthreads();
                #pragma unroll
                for (int r = 0; r < 4; r++) {
                    int pr = quad * 4 + r;
                    smem[F2T + pr * 128 + o1] = f2bf(lrelu(a1[r] + bb1));
                    smem[F2T + pr * 128 + o2] = f2bf(lrelu(a2[r] + bb2));
                }
            }
            __syncthreads();

            // GEMM1: h1 = leaky(m1 @ f2 + b1) -> LDS
            {
                f32x4 g1 = {0.f, 0.f, 0.f, 0.f};
                f32x4 g2 = {0.f, 0.f, 0.f, 0.f};
                #pragma unroll 2
                for (int s = 0; s < 4; s++) {
                    u32x4 av = *(const u32x4*)(smem + F2T + m * 128 + s * 32 + quad * 8);
                    u32x4 bv1 = *(const u32x4*)(m1P + (((size_t)(s * 8 + wv) * 64 + lane) << 3));
                    u32x4 bv2 = *(const u32x4*)(m1P + (((size_t)(s * 8 + wv + 4) * 64 + lane) << 3));
                    g1 = __builtin_amdgcn_mfma_f32_16x16x32_bf16(
                        __builtin_bit_cast(bf16x8, av), __builtin_bit_cast(bf16x8, bv1), g1, 0, 0, 0);
                    g2 = __builtin_amdgcn_mfma_f32_16x16x32_bf16(
                        __builtin_bit_cast(bf16x8, av), __builtin_bit_cast(bf16x8, bv2), g2, 0, 0, 0);
                }
                int o1 = wv * 16 + col, o2 = (wv + 4) * 16 + col;
                float bb1 = m1_b[o1], bb2 = m1_b[o2];
                #pragma unroll
                for (int r = 0; r < 4; r++) {
                    int pr = quad * 4 + r;
                    smem[H1OFF + pr * 136 + o1] = f2bf(lrelu(g1[r] + bb1));
                    smem[H1OFF + pr * 136 + o2] = f2bf(lrelu(g2[r] + bb2));
                }
            }
            __syncthreads();

            // GEMM2: flow_feat = leaky(m2 @ h1 + b2) -> dout + ff (fp32 LDS)
            {
                float* ffp = (float*)(smem + FFOFF);
                f32x4 g = {0.f, 0.f, 0.f, 0.f};
                #pragma unroll 2
                for (int s = 0; s < 4; s++) {
                    u32x4 av = *(const u32x4*)(smem + H1OFF + m * 136 + s * 32 + quad * 8);
                    u32x4 bv = *(const u32x4*)(m2P + (((size_t)(s * 4 + wv) * 64 + lane) << 3));
                    g = __builtin_amdgcn_mfma_f32_16x16x32_bf16(
                        __builtin_bit_cast(bf16x8, av), __builtin_bit_cast(bf16x8, bv), g, 0, 0, 0);
                }
                int o = wv * 16 + col;
                float bb = m2_b[o];
                #pragma unroll
                for (int r = 0; r < 4; r++) {
                    int pr = quad * 4 + r;
                    float v = lrelu(g[r] + bb);
                    dout[((size_t)b * 64 + o) * NPTS + n0 + pr] = v;
                    ffp[pr * 68 + o] = v;
                }
            }
            __syncthreads();

            // flow = cl_w @ ff + cl_b  (rolled)
            if (t < 48) {
                float* ffp = (float*)(smem + FFOFF);
                int pp = t & 15, oo = t >> 4;
                float a = cl_b[oo];
                #pragma unroll 8
                for (int i = 0; i < 64; i++)
                    a += cl_w[oo * 64 + i] * ffp[pp * 68 + i];
                dout[(size_t)NB * 64 * NPTS + ((size_t)b * 3 + oo) * NPTS + n0 + pp] = a;
            }
            __syncthreads();   // ffp/F2T region dead before next tile's DMA
        }
    }
}

// ---------------------------------------------------------------------------
extern "C" void kernel_launch(void* const* d_in, const int* in_sizes, int n_in,
                              void* d_out, int out_size, void* d_ws, size_t ws_size,
                              hipStream_t stream) {
    const float* xyz   = (const float*)d_in[0];
    const float* feat  = (const float*)d_in[1];
    const int*   knn   = (const int*)d_in[2];
    const float* wn1_w = (const float*)d_in[3];
    const float* wn1_b = (const float*)d_in[4];
    const float* lin1w = (const float*)d_in[5];
    const float* lin1b = (const float*)d_in[6];
    const float* wn2_w = (const float*)d_in[7];
    const float* wn2_b = (const float*)d_in[8];
    const float* lin2w = (const float*)d_in[9];
    const float* lin2b = (const float*)d_in[10];
    const float* m1_w  = (const float*)d_in[11];
    const float* m1_b  = (const float*)d_in[12];
    const float* m2_w  = (const float*)d_in[13];
    const float* m2_b  = (const float*)d_in[14];
    const float* cl_w  = (const float*)d_in[15];
    const float* cl_b  = (const float*)d_in[16];
    float* out = (float*)d_out;

    char* ws = (char*)d_ws;
    u16*   fcT1 = (u16*)(ws);                      // BN*136*2 = 8,912,896
    u16*   fcT2 = (u16*)(ws + 8912896);            // 8,912,896
    float* xyzF = (float*)(ws + 17825792);         // 524,288
    u16*   lw1P = (u16*)(ws + 18350080);           // 278,528
    u16*   lw2P = (u16*)(ws + 18628608);           // 278,528
    u16*   m1P  = (u16*)(ws + 18907136);           // 32,768
    u16*   m2P  = (u16*)(ws + 18939904);           // 16,384 -> total 18,956,288

    (void)in_sizes; (void)n_in; (void)out_size; (void)ws_size;

    fused_all<<<dim3(NBLK), dim3(256), 0, stream>>>(
        xyz, feat, knn,
        wn1_w, wn1_b, lin1w, lin1b,
        wn2_w, wn2_b, lin2w, lin2b,
        m1_w, m1_b, m2_w, m2_b,
        cl_w, cl_b, out,
        fcT1, fcT2, xyzF, lw1P, lw2P, m1P, m2P);
}

// Round 9
// 188.608 us; speedup vs baseline: 2.9356x; 2.9356x over previous
//
#include <hip/hip_runtime.h>

typedef __bf16 bf16x8 __attribute__((ext_vector_type(8)));
typedef float  f32x4  __attribute__((ext_vector_type(4)));
typedef float  f32x2  __attribute__((ext_vector_type(2)));
typedef unsigned int u32x4 __attribute__((ext_vector_type(4)));
typedef unsigned short u16;

#define NPTS 8192
#define NB   4
#define KNN  16
#define ROW  136        // u16 per row; 272 B = 17 x 16B
#define CF   131
#define JBLK 136
#define NSTEP 34        // K = 1088 = 34*32
#define AGG_STRIDE 1096 // u16 (2192 B per point)
#define HALF_U16 8704   // 64 rows * 136 u16 per ping-pong half
#define WOFF  17408     // u16 idx: w bf16 [16p][16k][8j]
#define RBOFF 19456     // u16 idx: rb table (u16[256])
#define SMEM_U16 19712  // 39424 B total
// mode-1 tail aliases (all inside dead rowbuf/agg region)
#define F2T   0         // u16[16][128]
#define H1OFF 2304      // u16, stride 136
#define FFOFF 4608      // u16 idx -> float* (byte 9216), stride 68 floats
#define NEG 0.1f

#define WAITVM(n) __builtin_amdgcn_s_waitcnt(0x0F70 | (n))
#define SB() __builtin_amdgcn_sched_barrier(0)

__device__ __forceinline__ float b2f(u16 h) {
    return __uint_as_float(((unsigned int)h) << 16);
}
// round-half-up: 2 insts; <=1 ulp bf16
__device__ __forceinline__ u16 f2bf(float f) {
    unsigned int u = __float_as_uint(f);
    return (u16)((u + 0x8000u) >> 16);
}
__device__ __forceinline__ void dma16(const u16* g, u16* l) {
    __builtin_amdgcn_global_load_lds(
        (const __attribute__((address_space(1))) void*)g,
        (__attribute__((address_space(3))) void*)l, 16, 0, 0);
}
__device__ __forceinline__ float lrelu(float v) {
    return (v < 0.0f) ? NEG * v : v;
}

// ---------------------------------------------------------------------------
// Merged pack kernel. Blocks [0,512): fcT1/fcT2/xyzF pack.
// Blocks [512,660): weight packs (lw1 68, lw2 68, m1 8, m2 4).
// Writeback vectorized: 17 x ushort8 units per row, one dwordx4 store each.
__global__ __launch_bounds__(256) void pack_all(
    const float* __restrict__ xyz, const float* __restrict__ feat,
    u16* __restrict__ fcT1, u16* __restrict__ fcT2, float* __restrict__ xyzF,
    const float* __restrict__ l1, const float* __restrict__ l2,
    const float* __restrict__ w1, const float* __restrict__ w2,
    u16* __restrict__ o1, u16* __restrict__ o2,
    u16* __restrict__ o3, u16* __restrict__ o4)
{
    int t = threadIdx.x;
    if (blockIdx.x < 512) {
        __shared__ u16 tile[CF * 65];
        int blk = blockIdx.x;
        int b = blk >> 7;
        int n0 = (blk & 127) << 6;
        int nn = t & 63;
        #pragma unroll 1
        for (int c = (t >> 6); c < CF; c += 4) {
            float v;
            if (c < 3) v = xyz[(size_t)b * 3 * NPTS + (size_t)c * NPTS + n0 + nn];
            else       v = feat[(size_t)b * 128 * NPTS + (size_t)(c - 3) * NPTS + n0 + nn];
            tile[c * 65 + nn] = f2bf(v);
            if (c < 3) xyzF[((size_t)b * NPTS + n0 + nn) * 4 + c] = v;
        }
        __syncthreads();
        // 64 rows x 17 ushort8 units; fcT2 needs only units 0 and 16.
        #pragma unroll 1
        for (int e = t; e < 64 * 17; e += 256) {
            int r = e / 17;
            int u = e - r * 17;
            int c0 = u * 8;
            unsigned int w[4];
            #pragma unroll
            for (int i = 0; i < 4; i++) {
                int ca = c0 + 2 * i, cb = ca + 1;
                unsigned lo = (ca < CF) ? (unsigned)tile[ca * 65 + r] : 0u;
                unsigned hi = (cb < CF) ? (unsigned)tile[cb * 65 + r] : 0u;
                w[i] = lo | (hi << 16);
            }
            size_t row = (size_t)b * NPTS + n0 + r;
            *(u32x4*)(fcT1 + row * ROW + c0) = (u32x4){w[0], w[1], w[2], w[3]};
            if (u == 0 || u == 16)
                *(u32x4*)(fcT2 + row * ROW + c0) = (u32x4){w[0], w[1], w[2], w[3]};
        }
    } else {
        int blk = blockIdx.x - 512;
        const float* w; u16* out; int O, Cin, remap, b0;
        if (blk < 68)       { w = l1; out = o1; O = 128; Cin = 1048; remap = 1; b0 = 0; }
        else if (blk < 136) { w = l2; out = o2; O = 128; Cin = 1048; remap = 1; b0 = 68; }
        else if (blk < 144) { w = w1; out = o3; O = 128; Cin = 128;  remap = 0; b0 = 136; }
        else                { w = w2; out = o4; O = 64;  Cin = 128;  remap = 0; b0 = 144; }
        int T = O >> 4;
        int tid = (blk - b0) * 256 + t;
        int l = tid & 63;
        int st = tid >> 6;
        int tt = st % T;
        int s = st / T;
        int o = tt * 16 + (l & 15);
        int kb = s * 32 + ((l >> 4) * 8);
        #pragma unroll 1
        for (int j = 0; j < 8; j++) {
            int kh = kb + j;
            u16 v = 0;
            if (remap) {
                int jj = kh / JBLK, cc = kh - jj * JBLK;
                if (cc < CF) v = f2bf(w[(size_t)o * Cin + jj * CF + cc]);
            } else {
                if (kh < Cin) v = f2bf(w[(size_t)o * Cin + kh]);
            }
            out[(size_t)tid * 8 + j] = v;
        }
    }
}

// ---------------------------------------------------------------------------
// Core: gather (pipelined DMA) + weight-net + einsum + MFMA GEMM vs lwP.
// (Exact round-0 structure: VGPR 68, 2 barriers, WAITVM depth 5.)
__device__ __forceinline__ void pc_core(
    u16* __restrict__ smem,
    const u16* __restrict__ fcT, const float* __restrict__ xyzF,
    const int* __restrict__ knn, const float* __restrict__ wn_w,
    const float* __restrict__ wn_b, const u16* __restrict__ lwP,
    int pt0, int b, int n0, f32x4& acc1o, f32x4& acc2o)
{
    int t = threadIdx.x;
    int wv = t >> 6, lane = t & 63;
    int p = t >> 4, cl = t & 15;
    u16* rb16 = smem + RBOFF;

    // ---- P0 (wave-local): indices, rel coords, weight-net -> bf16 LDS ----
    {
        size_t rowC = (size_t)b * NPTS + n0 + p;
        int idxv = knn[rowC * KNN + cl];
        int rb = b * NPTS + idxv;
        rb16[p * 16 + cl] = (u16)rb;
        f32x4 cx = *(const f32x4*)(xyzF + rowC * 4);
        f32x4 nx = *(const f32x4*)(xyzF + (size_t)rb * 4);
        float rx = nx[0] - cx[0], ry = nx[1] - cx[1], rz = nx[2] - cx[2];
        unsigned int wp[4];
        #pragma unroll
        for (int jj = 0; jj < 4; jj++) {
            float a0 = lrelu(wn_w[(2 * jj) * 3 + 0] * rx + wn_w[(2 * jj) * 3 + 1] * ry +
                             wn_w[(2 * jj) * 3 + 2] * rz + wn_b[2 * jj]);
            float a1 = lrelu(wn_w[(2 * jj + 1) * 3 + 0] * rx + wn_w[(2 * jj + 1) * 3 + 1] * ry +
                             wn_w[(2 * jj + 1) * 3 + 2] * rz + wn_b[2 * jj + 1]);
            wp[jj] = (unsigned)f2bf(a0) | ((unsigned)f2bf(a1) << 16);
        }
        *(u32x4*)(smem + WOFF + (p * 16 + cl) * 8) = (u32x4){wp[0], wp[1], wp[2], wp[3]};
    }

    f32x2 acc[4][8];
    float acct[8];
    #pragma unroll
    for (int i = 0; i < 4; i++)
        #pragma unroll
        for (int j = 0; j < 8; j++) acc[i][j] = (f32x2){0.f, 0.f};
    #pragma unroll
    for (int j = 0; j < 8; j++) acct[j] = 0.f;

    // ---- hoisted DMA slot decomposition (chunk-invariant) ----
    int rbidx[5], remu[5], ldso[5];
    #pragma unroll
    for (int i = 0; i < 5; i++) {
        int slot = i * 64 + lane;
        int rl = slot / 17;              // 0..15 (row within wave's chunk)
        int rem = slot - rl * 17;        // 0..16 (16B unit within row)
        int pp = wv * 4 + (rl >> 2);
        int kk = rl & 3;
        rbidx[i] = pp * 16 + kk;         // + c*4 per chunk
        remu[i] = rem * 8;               // u16 offset in row
        ldso[i] = (pp * 4 + kk) * 136 + rem * 8;
    }

    auto issue = [&](int c) {
        int h = c & 1;
        #pragma unroll
        for (int i = 0; i < 5; i++) {
            if (i < 4 || lane < 16) {
                int rb = (int)rb16[rbidx[i] + c * 4];
                dma16(fcT + (size_t)rb * ROW + remu[i],
                      smem + h * HALF_U16 + ldso[i]);
            }
        }
    };
    // consume chunk c: einsum over its 4 k's (LDS only)
    auto consume = [&](int c) {
        int h = c & 1;
        const u16* rpb = smem + h * HALF_U16 + p * (4 * 136);
        const u16* wpb = smem + WOFF + (p * 16 + c * 4) * 8;
        #pragma unroll 2
        for (int kk = 0; kk < 4; kk++) {
            u32x4 rv = *(const u32x4*)(rpb + kk * 136 + cl * 8);
            float tl = (cl < 3) ? b2f(rpb[kk * 136 + 128 + cl]) : 0.0f;
            u32x4 wv4 = *(const u32x4*)(wpb + kk * 8);
            f32x2 v[4];
            float wr[8];
            #pragma unroll
            for (int i = 0; i < 4; i++) {
                unsigned int u = rv[i];
                v[i] = (f32x2){__uint_as_float(u << 16),
                               __uint_as_float(u & 0xFFFF0000u)};
                unsigned int uw = wv4[i];
                wr[2 * i]     = __uint_as_float(uw << 16);
                wr[2 * i + 1] = __uint_as_float(uw & 0xFFFF0000u);
            }
            #pragma unroll
            for (int j = 0; j < 8; j++) {
                f32x2 w2 = (f32x2){wr[j], wr[j]};
                #pragma unroll
                for (int i = 0; i < 4; i++) acc[i][j] += v[i] * w2;
                acct[j] += tl * wr[j];
            }
        }
    };

    issue(0); issue(1);
    #pragma unroll 1
    for (int c = 0; c < 2; c++) {
        WAITVM(5); SB(); consume(c); SB(); issue(c + 2); SB();
    }
    WAITVM(5); SB(); consume(2); SB();
    WAITVM(0); SB(); consume(3);
    __syncthreads();   // all einsum reads done before agg overwrites rowbuf

    // ---- agg write (bf16, k-hat layout) ----
    {
        #pragma unroll
        for (int j = 0; j < 8; j++) {
            unsigned int o[4];
            #pragma unroll
            for (int i = 0; i < 4; i++) {
                unsigned int lo = f2bf(acc[i][j].x);
                unsigned int hi = f2bf(acc[i][j].y);
                o[i] = lo | (hi << 16);
            }
            *(u32x4*)(smem + p * AGG_STRIDE + j * JBLK + cl * 8) =
                (u32x4){o[0], o[1], o[2], o[3]};
        }
        if (cl < 3) {
            #pragma unroll
            for (int j = 0; j < 8; j++)
                smem[p * AGG_STRIDE + j * JBLK + 128 + cl] = f2bf(acct[j]);
        }
        if (cl < 5) {
            #pragma unroll
            for (int j = 0; j < 8; j++)
                smem[p * AGG_STRIDE + j * JBLK + CF + cl] = 0;
        }
    }
    __syncthreads();

    // ---- MFMA: out[16][128] = agg @ lin_w^T. Rolled, unroll-4 ----
    {
        int m = lane & 15, quad = lane >> 4;
        f32x4 a1 = {0.f, 0.f, 0.f, 0.f};
        f32x4 a2 = {0.f, 0.f, 0.f, 0.f};
        #pragma unroll 4
        for (int s = 0; s < NSTEP; s++) {
            u32x4 av = *(const u32x4*)(smem + m * AGG_STRIDE + s * 32 + quad * 8);
            u32x4 bv1 = *(const u32x4*)(lwP + (((size_t)(s * 8 + wv) * 64 + lane) << 3));
            u32x4 bv2 = *(const u32x4*)(lwP + (((size_t)(s * 8 + wv + 4) * 64 + lane) << 3));
            a1 = __builtin_amdgcn_mfma_f32_16x16x32_bf16(
                __builtin_bit_cast(bf16x8, av), __builtin_bit_cast(bf16x8, bv1), a1, 0, 0, 0);
            a2 = __builtin_amdgcn_mfma_f32_16x16x32_bf16(
                __builtin_bit_cast(bf16x8, av), __builtin_bit_cast(bf16x8, bv2), a2, 0, 0, 0);
        }
        acc1o = a1; acc2o = a2;
    }
}

// XCD-aware tile swizzle: 2048 tiles, 8 XCDs, 2048%8==0 -> bijective.
// XCD x owns tiles [x*256, (x+1)*256) = half of one batch; per-XCD L2
// working set (fcT slice 2.23MB + lwP 0.27MB + knn/xyzF) fits 4MB L2.
__device__ __forceinline__ int tile_swz(int bid) {
    return (bid & 7) * 256 + (bid >> 3);
}

// ---------------------------------------------------------------------------
// pc #1: writes bf16 rows into fcT2 at col offset 3.
__global__ __launch_bounds__(256) void pc_kernel0(
    const u16* __restrict__ fcT, const float* __restrict__ xyzF,
    const int* __restrict__ knn, const float* __restrict__ wn_w,
    const float* __restrict__ wn_b, const u16* __restrict__ lwP,
    const float* __restrict__ lin_b, u16* __restrict__ out)
{
    __shared__ __align__(16) u16 smem[SMEM_U16];
    int t = threadIdx.x;
    int wv = t >> 6, lane = t & 63;
    int pt0 = tile_swz(blockIdx.x) * 16;
    int b = pt0 >> 13;
    int n0 = pt0 & (NPTS - 1);
    f32x4 a1, a2;
    pc_core(smem, fcT, xyzF, knn, wn_w, wn_b, lwP, pt0, b, n0, a1, a2);
    int col = lane & 15, quad = lane >> 4;
    int o1 = wv * 16 + col, o2 = (wv + 4) * 16 + col;
    float bb1 = lin_b[o1], bb2 = lin_b[o2];
    #pragma unroll
    for (int r = 0; r < 4; r++) {
        int prow = pt0 + quad * 4 + r;
        out[(size_t)prow * ROW + 3 + o1] = f2bf(lrelu(a1[r] + bb1));
        out[(size_t)prow * ROW + 3 + o2] = f2bf(lrelu(a2[r] + bb2));
    }
}

// ---------------------------------------------------------------------------
// pc #2 fused with the MLP head: f2 stays in LDS; writes fp32 d_out.
__global__ __launch_bounds__(256) void pc_kernel1(
    const u16* __restrict__ fcT, const float* __restrict__ xyzF,
    const int* __restrict__ knn, const float* __restrict__ wn_w,
    const float* __restrict__ wn_b, const u16* __restrict__ lwP,
    const float* __restrict__ lin_b,
    const u16* __restrict__ m1P, const float* __restrict__ m1_b,
    const u16* __restrict__ m2P, const float* __restrict__ m2_b,
    const float* __restrict__ cl_w, const float* __restrict__ cl_b,
    float* __restrict__ dout)
{
    __shared__ __align__(16) u16 smem[SMEM_U16];
    int t = threadIdx.x;
    int wv = t >> 6, lane = t & 63;
    int pt0 = tile_swz(blockIdx.x) * 16;
    int b = pt0 >> 13;
    int n0 = pt0 & (NPTS - 1);
    f32x4 a1, a2;
    pc_core(smem, fcT, xyzF, knn, wn_w, wn_b, lwP, pt0, b, n0, a1, a2);
    int col = lane & 15, quad = lane >> 4;
    int m = lane & 15;

    // f2 tile -> LDS (agg region is done being read after this barrier)
    {
        int o1 = wv * 16 + col, o2 = (wv + 4) * 16 + col;
        float bb1 = lin_b[o1], bb2 = lin_b[o2];
        __syncthreads();
        #pragma unroll
        for (int r = 0; r < 4; r++) {
            int pr = quad * 4 + r;
            smem[F2T + pr * 128 + o1] = f2bf(lrelu(a1[r] + bb1));
            smem[F2T + pr * 128 + o2] = f2bf(lrelu(a2[r] + bb2));
        }
    }
    __syncthreads();

    // GEMM1: h1 = leaky(m1 @ f2 + b1) -> LDS
    {
        f32x4 g1 = {0.f, 0.f, 0.f, 0.f};
        f32x4 g2 = {0.f, 0.f, 0.f, 0.f};
        #pragma unroll 2
        for (int s = 0; s < 4; s++) {
            u32x4 av = *(const u32x4*)(smem + F2T + m * 128 + s * 32 + quad * 8);
            u32x4 bv1 = *(const u32x4*)(m1P + (((size_t)(s * 8 + wv) * 64 + lane) << 3));
            u32x4 bv2 = *(const u32x4*)(m1P + (((size_t)(s * 8 + wv + 4) * 64 + lane) << 3));
            g1 = __builtin_amdgcn_mfma_f32_16x16x32_bf16(
                __builtin_bit_cast(bf16x8, av), __builtin_bit_cast(bf16x8, bv1), g1, 0, 0, 0);
            g2 = __builtin_amdgcn_mfma_f32_16x16x32_bf16(
                __builtin_bit_cast(bf16x8, av), __builtin_bit_cast(bf16x8, bv2), g2, 0, 0, 0);
        }
        int o1 = wv * 16 + col, o2 = (wv + 4) * 16 + col;
        float bb1 = m1_b[o1], bb2 = m1_b[o2];
        #pragma unroll
        for (int r = 0; r < 4; r++) {
            int pr = quad * 4 + r;
            smem[H1OFF + pr * 136 + o1] = f2bf(lrelu(g1[r] + bb1));
            smem[H1OFF + pr * 136 + o2] = f2bf(lrelu(g2[r] + bb2));
        }
    }
    __syncthreads();

    // GEMM2: flow_feat = leaky(m2 @ h1 + b2) -> d_out + ff (fp32 LDS)
    {
        float* ffp = (float*)(smem + FFOFF);
        f32x4 g = {0.f, 0.f, 0.f, 0.f};
        #pragma unroll 2
        for (int s = 0; s < 4; s++) {
            u32x4 av = *(const u32x4*)(smem + H1OFF + m * 136 + s * 32 + quad * 8);
            u32x4 bv = *(const u32x4*)(m2P + (((size_t)(s * 4 + wv) * 64 + lane) << 3));
            g = __builtin_amdgcn_mfma_f32_16x16x32_bf16(
                __builtin_bit_cast(bf16x8, av), __builtin_bit_cast(bf16x8, bv), g, 0, 0, 0);
        }
        int o = wv * 16 + col;
        float bb = m2_b[o];
        #pragma unroll
        for (int r = 0; r < 4; r++) {
            int pr = quad * 4 + r;
            float v = lrelu(g[r] + bb);
            dout[((size_t)b * 64 + o) * NPTS + n0 + pr] = v;
            ffp[pr * 68 + o] = v;
        }
    }
    __syncthreads();

    // flow = cl_w @ ff + cl_b  (rolled)
    if (t < 48) {
        float* ffp = (float*)(smem + FFOFF);
        int pp = t & 15, oo = t >> 4;
        float a = cl_b[oo];
        #pragma unroll 8
        for (int i = 0; i < 64; i++)
            a += cl_w[oo * 64 + i] * ffp[pp * 68 + i];
        dout[(size_t)NB * 64 * NPTS + ((size_t)b * 3 + oo) * NPTS + n0 + pp] = a;
    }
}

// ---------------------------------------------------------------------------
extern "C" void kernel_launch(void* const* d_in, const int* in_sizes, int n_in,
                              void* d_out, int out_size, void* d_ws, size_t ws_size,
                              hipStream_t stream) {
    const float* xyz   = (const float*)d_in[0];
    const float* feat  = (const float*)d_in[1];
    const int*   knn   = (const int*)d_in[2];
    const float* wn1_w = (const float*)d_in[3];
    const float* wn1_b = (const float*)d_in[4];
    const float* lin1w = (const float*)d_in[5];
    const float* lin1b = (const float*)d_in[6];
    const float* wn2_w = (const float*)d_in[7];
    const float* wn2_b = (const float*)d_in[8];
    const float* lin2w = (const float*)d_in[9];
    const float* lin2b = (const float*)d_in[10];
    const float* m1_w  = (const float*)d_in[11];
    const float* m1_b  = (const float*)d_in[12];
    const float* m2_w  = (const float*)d_in[13];
    const float* m2_b  = (const float*)d_in[14];
    const float* cl_w  = (const float*)d_in[15];
    const float* cl_b  = (const float*)d_in[16];
    float* out = (float*)d_out;

    char* ws = (char*)d_ws;
    const size_t BN = (size_t)NB * NPTS;
    u16*   fcT1 = (u16*)(ws);                      // BN*136*2 = 8,912,896
    u16*   fcT2 = (u16*)(ws + 8912896);            // 8,912,896
    float* xyzF = (float*)(ws + 17825792);         // 524,288
    u16*   lw1P = (u16*)(ws + 18350080);           // 278,528
    u16*   lw2P = (u16*)(ws + 18628608);           // 278,528
    u16*   m1P  = (u16*)(ws + 18907136);           // 32,768
    u16*   m2P  = (u16*)(ws + 18939904);           // 16,384 -> total 18,956,288

    (void)in_sizes; (void)n_in; (void)out_size; (void)ws_size;

    pack_all<<<dim3(660), dim3(256), 0, stream>>>(
        xyz, feat, fcT1, fcT2, xyzF,
        lin1w, lin2w, m1_w, m2_w, lw1P, lw2P, m1P, m2P);
    pc_kernel0<<<dim3(BN / 16), dim3(256), 0, stream>>>(
        fcT1, xyzF, knn, wn1_w, wn1_b, lw1P, lin1b, fcT2);
    pc_kernel1<<<dim3(BN / 16), dim3(256), 0, stream>>>(
        fcT2, xyzF, knn, wn2_w, wn2_b, lw2P, lin2b,
        m1P, m1_b, m2P, m2_b, cl_w, cl_b, out);
}